// Round 13
// baseline (2097.730 us; speedup 1.0000x reference)
//
#include <hip/hip_runtime.h>
#include <hip/hip_bf16.h>
#include <stdint.h>

#define N_OUT 512
#define N_IN 64
#define BM 64                   // batch rows per block
#define NSLAB 18                // K-steps of 32 (576 total)
#define THREADS 1024

// LDS map (151552 B -> 1 block/CU):
//  [0,65536)        bbuf0: weight slab  [mat][512 col][4 lg][16B]
//  [65536,131072)   bbuf1: weight slab (double buffer)
//  [131072,147456)  xring: 4 slots x [64 row][32 k]x2B (4096 B/slot)
//  [147456,151552)  lsum:  [16 wave][64 row] f32
#define BBUF0 0
#define BBUF1 65536
#define XRING 131072
#define LSUM  147456
#define LDS_TOTAL 151552

typedef __attribute__((ext_vector_type(8))) short short8_t;   // 8 bf16
typedef __attribute__((ext_vector_type(4))) float f32x4;
typedef __attribute__((ext_vector_type(2))) float f32x2;
typedef unsigned short u16;
typedef unsigned int u32;

__device__ __forceinline__ u16 f2bf(float f) {
    __hip_bfloat16 h = __float2bfloat16(f);
    return *reinterpret_cast<u16*>(&h);
}
__device__ __forceinline__ float bf2f(u16 u) {
    union { u32 u; float f; } v;
    v.u = ((u32)u) << 16;
    return v.f;
}

// Prep: masked bf16 weights in k-slab-major layout:
//   Wp[(((s*2+mat)*512 + col)*4 + lg)*8 + j] = W[col][s*32 + lg*8 + j], 0 if masked
// so slab s is contiguous per mat and gload_lds staging is lane-linear.
__global__ void prep_weights_kernel(const float* __restrict__ PA,
                                    const float* __restrict__ PB,
                                    u16* __restrict__ Wp) {
    const int col = blockIdx.x;
    const int lim = N_IN + col;
    const float* src[2] = { PA + (size_t)col * (N_IN + N_OUT),
                            PB + (size_t)col * (N_IN + N_OUT) };
    for (int k = threadIdx.x; k < N_IN + N_OUT; k += blockDim.x) {
        int s = k >> 5, lg = (k >> 3) & 3, j = k & 7;
        bool valid = (k < lim);
        #pragma unroll
        for (int mat = 0; mat < 2; ++mat) {
            size_t dst = ((size_t)(((s * 2 + mat) * N_OUT + col) * 4 + lg)) * 8 + j;
            Wp[dst] = valid ? f2bf(src[mat][k]) : (u16)0;
        }
    }
}

// m97-style fused kernel: BM=64, 16 waves, 1 block/CU.
// Weights: LDS double-buffer via global_load_lds (2-phase: stage s+1, compute s,
// one barrier). x: rolling 4-slot bf16 ring; slab s serves BOTH the A-operand of
// step s AND the epilogue-X of the column pair finishing at step s (k = 64+col).
// Wave w owns 16-col frags {w, 31-w}: exactly 21 active frag-steps each (balanced).
__global__ __launch_bounds__(THREADS)
__attribute__((amdgpu_waves_per_eu(4, 4)))
void maf_main_kernel(const float* __restrict__ X,
                     const float* __restrict__ Cc,
                     const u16* __restrict__ Wp,
                     float* __restrict__ Z,
                     float* __restrict__ LD) {
    extern __shared__ char smem[];
    const int tid = threadIdx.x;
    const int r0 = blockIdx.x * BM;

    const int wid  = tid >> 6;
    const int lane = tid & 63;
    const int lr = lane & 15;          // fragment row (A) / col (B, C/D)
    const int lg = lane >> 4;          // k-octet (A,B) / row-quad (C/D)

    const int fA = wid, fB = 31 - wid;                 // 16-col fragments
    const int ksA = ((79 + 16 * fA) >> 5) + 1;          // active steps of a frag
    const int ksB = ((79 + 16 * fB) >> 5) + 1;

    const int xrow = tid >> 4;                          // staging roles
    const int xco  = (tid & 15) * 2;

    // ---------- prologue ----------
    {   // c -> slabs 0,1 (k in [0,64)): f32x4 per thread
        int k = (tid & 15) * 4;
        f32x4 v = __builtin_nontemporal_load(
            (const f32x4*)(Cc + (size_t)(r0 + xrow) * N_IN + k));
        u32 p0 = (u32)f2bf(v[0]) | ((u32)f2bf(v[1]) << 16);
        u32 p1 = (u32)f2bf(v[2]) | ((u32)f2bf(v[3]) << 16);
        char* d = smem + XRING + (k >> 5) * 4096 + xrow * 64 + (k & 31) * 2;
        *(u32*)d = p0;
        *(u32*)(d + 4) = p1;
    }
    {   // X cols [0,32) -> slab 2
        f32x2 v = __builtin_nontemporal_load(
            (const f32x2*)(X + (size_t)(r0 + xrow) * N_OUT + xco));
        u32 p = (u32)f2bf(v[0]) | ((u32)f2bf(v[1]) << 16);
        *(u32*)(smem + XRING + 2 * 4096 + xrow * 64 + xco * 2) = p;
    }
    // weight slab 0 -> bbuf0 (full 512 cols, 4096 chunks)
    {
        #pragma unroll
        for (int i = 0; i < 4; ++i) {
            int c = tid + i * THREADS;               // chunk in [mat][col][lg] order
            const u16* g = Wp + (size_t)c * 8;       // s2=0, clo=0: identical order
            char* l = smem + BBUF0 + (size_t)c * 16;
            __builtin_amdgcn_global_load_lds(
                (const __attribute__((address_space(1))) u32*)g,
                (__attribute__((address_space(3))) u32*)l, 16, 0, 0);
        }
    }
    // issue x regs for slab 3 (X cols [32,64))
    f32x2 xrA = __builtin_nontemporal_load(
        (const f32x2*)(X + (size_t)(r0 + xrow) * N_OUT + 32 + xco));
    f32x2 xrB;
    __syncthreads();

    f32x4 aAE[4], aAV[4], aBE[4], aBV[4];
    #pragma unroll
    for (int m = 0; m < 4; ++m) {
        aAE[m] = (f32x4)(0.0f); aAV[m] = (f32x4)(0.0f);
        aBE[m] = (f32x4)(0.0f); aBV[m] = (f32x4)(0.0f);
    }

    const int cA = (fA << 4) + lr;      // global cols of this wave's frags
    const int cB = (fB << 4) + lr;

    // ---------- K loop: manual 2x unroll for x-reg double buffer ----------
    for (int sp = 0; sp < NSLAB; sp += 2) {
        #pragma unroll
        for (int half = 0; half < 2; ++half) {
            const int s = sp + half;
            f32x2& xw = half ? xrB : xrA;   // write slab s+3 from this
            f32x2& xi = half ? xrA : xrB;   // issue slab s+4 into this

            // 1) stage weight slab s+1 into other buffer (shrinking col range)
            if (s + 1 < NSLAB) {
                const int s2 = s + 1;
                const int clo = (s2 >= 2) ? 32 * (s2 - 2) : 0;
                const int wm = (N_OUT - clo) * 4;        // chunks per mat (mult of 64)
                const int nch = wm * 2;
                char* dstb = smem + ((s2 & 1) ? BBUF1 : BBUF0);
                #pragma unroll
                for (int i = 0; i < 4; ++i) {
                    int c = tid + i * THREADS;
                    if (c < nch) {
                        int mat = (c >= wm) ? 1 : 0;
                        int r = c - mat * wm;
                        int col = clo + (r >> 2);
                        int lgc = r & 3;
                        const u16* g = Wp + ((size_t)(((s2 * 2 + mat) * N_OUT + col) * 4 + lgc)) * 8;
                        char* l = dstb + (((mat << 11) + (col << 2) + lgc) << 4);
                        __builtin_amdgcn_global_load_lds(
                            (const __attribute__((address_space(1))) u32*)g,
                            (__attribute__((address_space(3))) u32*)l, 16, 0, 0);
                    }
                }
            }
            // 2) issue X f32 loads for slab s+4 (held in regs across one barrier)
            if (s + 4 < NSLAB) {
                xi = __builtin_nontemporal_load(
                    (const f32x2*)(X + (size_t)(r0 + xrow) * N_OUT
                                   + ((s + 4) * 32 - 64) + xco));
            }
            // 3) compute step s from bbuf[s&1] + xring slot s&3
            const char* xs = smem + XRING + (s & 3) * 4096;
            const char* bb = smem + ((s & 1) ? BBUF1 : BBUF0);
            short8_t a[4];
            #pragma unroll
            for (int m = 0; m < 4; ++m)
                a[m] = *(const short8_t*)(xs + ((m << 4) + lr) * 64 + (lg << 4));
            if (s < ksA) {
                short8_t bE = *(const short8_t*)(bb + cA * 64 + (lg << 4));
                short8_t bV = *(const short8_t*)(bb + 32768 + cA * 64 + (lg << 4));
                #pragma unroll
                for (int m = 0; m < 4; ++m) {
                    aAE[m] = __builtin_amdgcn_mfma_f32_16x16x32_bf16(a[m], bE, aAE[m], 0, 0, 0);
                    aAV[m] = __builtin_amdgcn_mfma_f32_16x16x32_bf16(a[m], bV, aAV[m], 0, 0, 0);
                }
            }
            if (s < ksB) {
                short8_t bE = *(const short8_t*)(bb + cB * 64 + (lg << 4));
                short8_t bV = *(const short8_t*)(bb + 32768 + cB * 64 + (lg << 4));
                #pragma unroll
                for (int m = 0; m < 4; ++m) {
                    aBE[m] = __builtin_amdgcn_mfma_f32_16x16x32_bf16(a[m], bE, aBE[m], 0, 0, 0);
                    aBV[m] = __builtin_amdgcn_mfma_f32_16x16x32_bf16(a[m], bV, aBV[m], 0, 0, 0);
                }
            }
            // 4) inline epilogue for fragments completing at step s
            //    (their X cols live in THIS step's x-slab: k = 64+col in [32s,32s+32))
            if (s == ksA - 1 || s == ksB - 1) {
                const bool isA = (s == ksA - 1);
                const int f   = isA ? fA : fB;
                const f32x4* E = isA ? aAE : aBE;
                const f32x4* V = isA ? aAV : aBV;
                const int colg = (f << 4) + lr;
                const int kloc = 64 + (f << 4) - 32 * s + lr;    // 0..31
                #pragma unroll
                for (int m = 0; m < 4; ++m) {
                    #pragma unroll
                    for (int j = 0; j < 4; ++j) {
                        int row = (m << 4) + (lg << 2) + j;
                        float Xf = bf2f(*(const u16*)(xs + row * 64 + kloc * 2));
                        float Av = E[m][j];
                        Z[(size_t)(r0 + row) * N_OUT + colg] = Xf * __expf(Av) + V[m][j];
                    }
                }
                // log_det partial: reduce E over the 16 lanes sharing each row
                float* ls = (float*)(smem + LSUM) + (wid << 6);
                #pragma unroll
                for (int m = 0; m < 4; ++m) {
                    #pragma unroll
                    for (int j = 0; j < 4; ++j) {
                        float v = E[m][j];
                        v += __shfl_xor(v, 1);
                        v += __shfl_xor(v, 2);
                        v += __shfl_xor(v, 4);
                        v += __shfl_xor(v, 8);
                        if (lr == 0) {
                            int row = (m << 4) + (lg << 2) + j;
                            if (isA) ls[row] = v;       // fA always completes first
                            else     ls[row] += v;
                        }
                    }
                }
            }
            // 5) write x slab s+3 to ring (regs issued at step s-1 / prologue)
            if (s + 3 < NSLAB) {
                u32 p = (u32)f2bf(xw[0]) | ((u32)f2bf(xw[1]) << 16);
                *(u32*)(smem + XRING + ((s + 3) & 3) * 4096 + xrow * 64 + xco * 2) = p;
            }
            __syncthreads();
        }
    }

    // ---------- log_det final reduce ----------
    if (tid < BM) {
        const float* ls = (const float*)(smem + LSUM);
        float ssum = 0.0f;
        #pragma unroll
        for (int w = 0; w < 16; ++w) ssum += ls[(w << 6) + tid];
        LD[(size_t)r0 + tid] = ssum;
    }
}

extern "C" void kernel_launch(void* const* d_in, const int* in_sizes, int n_in,
                              void* d_out, int out_size, void* d_ws, size_t ws_size,
                              hipStream_t stream) {
    const float* X  = (const float*)d_in[0];
    const float* Cc = (const float*)d_in[1];
    const float* PA = (const float*)d_in[2];
    const float* PB = (const float*)d_in[3];

    u16* Wp = (u16*)d_ws;    // 18*2*512*4*8 u16 = 2.36 MB

    float* Z  = (float*)d_out;
    const size_t batch = (size_t)in_sizes[0] / N_OUT;   // 131072
    float* LD = Z + batch * N_OUT;

    prep_weights_kernel<<<N_OUT, 256, 0, stream>>>(PA, PB, Wp);

    (void)hipFuncSetAttribute((const void*)maf_main_kernel,
                              hipFuncAttributeMaxDynamicSharedMemorySize,
                              LDS_TOTAL);
    const int grid = (int)(batch / BM);                 // 2048
    maf_main_kernel<<<grid, THREADS, LDS_TOTAL, stream>>>(X, Cc, Wp, Z, LD);
}

// Round 14
// 304.142 us; speedup vs baseline: 6.8972x; 6.8972x over previous
//
#include <hip/hip_runtime.h>
#include <hip/hip_bf16.h>
#include <stdint.h>

#define N_OUT 512
#define N_IN 64
#define D_TOT 576               // N_IN + N_OUT
#define BM 128                  // batch rows per block
#define ROW_BYTES (D_TOT * 2)   // 1152 bytes per LDS x row (bf16)
#define XT_BYTES (BM * ROW_BYTES)          // 147456
#define LDS_TOTAL (XT_BYTES + 8 * 32 * 4)  // + lsum[8][32] = 148480

typedef __attribute__((ext_vector_type(8))) short short8_t;   // 8 x bf16
typedef __attribute__((ext_vector_type(4))) float f32x4;
typedef unsigned short u16;
typedef unsigned int u32;

__device__ __forceinline__ u16 f2bf(float f) {
    __hip_bfloat16 h = __float2bfloat16(f);
    return *reinterpret_cast<u16*>(&h);
}
__device__ __forceinline__ float bf2f(u16 u) {
    union { u32 u; float f; } v;
    v.u = ((u32)u) << 16;
    return v.f;
}

// Prep: masked bf16 weights, k-major fragment layout (R6 layout):
//   dst[((kk*4 + lg) * 512 + col) * 8 + j]  holds W[col][kk*32 + lg*8 + j]
// A wave's 16-col fragment load is 256 B contiguous.
__global__ void prep_weights_kernel(const float* __restrict__ PA,
                                    const float* __restrict__ PB,
                                    u16* __restrict__ WA,
                                    u16* __restrict__ WB) {
    const int col = blockIdx.x;
    const int lim = N_IN + col;
    const float* pa = PA + (size_t)col * D_TOT;
    const float* pb = PB + (size_t)col * D_TOT;
    for (int k = threadIdx.x; k < D_TOT; k += blockDim.x) {
        int kk = k >> 5, lg = (k >> 3) & 3, j = k & 7;
        size_t dst = ((size_t)(kk * 4 + lg) * N_OUT + col) * 8 + j;
        bool valid = (k < lim);
        WA[dst] = valid ? f2bf(pa[k]) : (u16)0;
        WB[dst] = valid ? f2bf(pb[k]) : (u16)0;
    }
}

// Main fused kernel — R14: wave->work mapping changed so waves differ in ROWS.
// BM=128, 512 threads, 1 block/CU. 8 waves = 4 row-strips (32 rows, m=2) x
// 2 phases. Each phase sweeps a balanced 8-group set in IDENTICAL order:
//   p=0: {0,3,4,7,8,11,12,15}   p=1: {1,2,5,6,9,10,13,14}   (both sum ks=84)
// The 4 waves of a phase issue the SAME weight addresses in loose lockstep ->
// 1 L2 miss + 3 L1 hits per line (R13 diagnosis: disjoint per-wave weight
// streams made every load an L2/L3-latency miss). Per-CU weight traffic also
// drops 4x (BM 32->128). No barriers in the K loop.
__global__ __launch_bounds__(512, 2)
void maf_main_kernel(const float* __restrict__ X,
                     const float* __restrict__ Cc,
                     const u16* __restrict__ WA,
                     const u16* __restrict__ WB,
                     float* __restrict__ Z,
                     float* __restrict__ LD) {
    extern __shared__ char smem[];
    char* xt = smem;                               // [128][1152] bf16, XOR-swizzled
    float* lsum = (float*)(smem + XT_BYTES);       // [8 wave][32 row]

    const int tid = threadIdx.x;
    const int r0 = blockIdx.x * BM;

    // ---- stage c (k in [0,64)) : 1024 chunks of 8 f32, 2 per thread ----
    #pragma unroll
    for (int i = 0; i < 2; ++i) {
        int id = tid + i * 512;
        int row = id >> 3, cc = id & 7;
        const float* src = Cc + (size_t)(r0 + row) * N_IN + cc * 8;
        f32x4 v0 = __builtin_nontemporal_load((const f32x4*)src);
        f32x4 v1 = __builtin_nontemporal_load((const f32x4*)(src + 4));
        short8_t p;
        p[0] = (short)f2bf(v0[0]); p[1] = (short)f2bf(v0[1]);
        p[2] = (short)f2bf(v0[2]); p[3] = (short)f2bf(v0[3]);
        p[4] = (short)f2bf(v1[0]); p[5] = (short)f2bf(v1[1]);
        p[6] = (short)f2bf(v1[2]); p[7] = (short)f2bf(v1[3]);
        int addr = (row * ROW_BYTES + cc * 16) ^ ((row & 7) << 4);
        *(short8_t*)(xt + addr) = p;
    }
    // ---- stage X (k in [64,576)) : 8192 chunks, 16 per thread ----
    #pragma unroll
    for (int i = 0; i < 16; ++i) {
        int id = tid + i * 512;
        int row = id >> 6, xc = id & 63;
        const float* src = X + (size_t)(r0 + row) * N_OUT + xc * 8;
        f32x4 v0 = __builtin_nontemporal_load((const f32x4*)src);
        f32x4 v1 = __builtin_nontemporal_load((const f32x4*)(src + 4));
        short8_t p;
        p[0] = (short)f2bf(v0[0]); p[1] = (short)f2bf(v0[1]);
        p[2] = (short)f2bf(v0[2]); p[3] = (short)f2bf(v0[3]);
        p[4] = (short)f2bf(v1[0]); p[5] = (short)f2bf(v1[1]);
        p[6] = (short)f2bf(v1[2]); p[7] = (short)f2bf(v1[3]);
        int addr = (row * ROW_BYTES + (8 + xc) * 16) ^ ((row & 7) << 4);
        *(short8_t*)(xt + addr) = p;
    }
    __syncthreads();

    const int wid  = tid >> 6;
    const int lane = tid & 63;
    const int lr = lane & 15;      // fragment row (A) / col (B, C/D)
    const int lg = lane >> 4;      // k-octet (A,B) / row-quad (C/D)
    const int p     = wid & 1;     // phase (group set)
    const int strip = wid >> 1;    // row strip: rows strip*32 .. +31
    const int rbase = strip << 5;

    float part[2][4];              // per-lane log_det partials [mm][j]
    #pragma unroll
    for (int mm = 0; mm < 2; ++mm)
        #pragma unroll
        for (int j = 0; j < 4; ++j) part[mm][j] = 0.0f;

    #pragma unroll
    for (int gi = 0; gi < 8; ++gi) {
        // balanced interleaved sets: g = 2*gi + (gi odd ? 1-p : p)
        const int g = (gi << 1) + ((gi & 1) ? (1 - p) : p);
        const int ks = 3 + g;              // causal: k < 64 + 32g + 32
        const int c0 = g << 5;

        f32x4 accE[2][2], accV[2][2];
        #pragma unroll
        for (int mm = 0; mm < 2; ++mm)
            #pragma unroll
            for (int n = 0; n < 2; ++n) {
                accE[mm][n] = (f32x4)(0.0f);
                accV[mm][n] = (f32x4)(0.0f);
            }

        #pragma unroll 2
        for (int kk = 0; kk < ks; ++kk) {
            short8_t a[2];
            #pragma unroll
            for (int mm = 0; mm < 2; ++mm) {
                int row = rbase + (mm << 4) + lr;
                int addr = (row * ROW_BYTES + kk * 64 + (lg << 4)) ^ ((row & 7) << 4);
                a[mm] = *(const short8_t*)(xt + addr);
            }
            short8_t bE[2], bV[2];
            const size_t wbase = (size_t)((kk << 2) + lg) * N_OUT + c0 + lr;
            #pragma unroll
            for (int n = 0; n < 2; ++n) {
                size_t off = (wbase + (n << 4)) * 8;
                bE[n] = *(const short8_t*)(WA + off);
                bV[n] = *(const short8_t*)(WB + off);
            }
            #pragma unroll
            for (int mm = 0; mm < 2; ++mm) {
                #pragma unroll
                for (int n = 0; n < 2; ++n) {
                    accE[mm][n] = __builtin_amdgcn_mfma_f32_16x16x32_bf16(a[mm], bE[n], accE[mm][n], 0, 0, 0);
                    accV[mm][n] = __builtin_amdgcn_mfma_f32_16x16x32_bf16(a[mm], bV[n], accV[mm][n], 0, 0, 0);
                }
            }
        }

        // ---- epilogue for this 32-col group ----
        // C/D layout (verified m89/m91): col = lane&15, row = (lane>>4)*4 + reg
        #pragma unroll
        for (int mm = 0; mm < 2; ++mm) {
            #pragma unroll
            for (int n = 0; n < 2; ++n) {
                int col = c0 + (n << 4) + lr;
                #pragma unroll
                for (int j = 0; j < 4; ++j) {
                    int row = rbase + (mm << 4) + (lg << 2) + j;
                    float Av = accE[mm][n][j];
                    float Bv = accV[mm][n][j];
                    int xaddr = (row * ROW_BYTES + (N_IN + col) * 2) ^ ((row & 7) << 4);
                    float Xf = bf2f(*(const u16*)(xt + xaddr));
                    Z[(size_t)(r0 + row) * N_OUT + col] = Xf * __expf(Av) + Bv;
                    part[mm][j] += Av;
                }
            }
        }
    }

    // ---- log_det: reduce across the 16 lanes (lr) sharing each row ----
    #pragma unroll
    for (int mm = 0; mm < 2; ++mm) {
        #pragma unroll
        for (int j = 0; j < 4; ++j) {
            float v = part[mm][j];
            v += __shfl_xor(v, 1);
            v += __shfl_xor(v, 2);
            v += __shfl_xor(v, 4);
            v += __shfl_xor(v, 8);
            if (lr == 0) lsum[(wid << 5) + (mm << 4) + (lg << 2) + j] = v;
        }
    }
    __syncthreads();
    if (tid < BM) {
        int sw = (tid >> 5) << 1, rloc = tid & 31;   // two phase-waves per strip
        LD[(size_t)r0 + tid] = lsum[(sw << 5) + rloc] + lsum[((sw + 1) << 5) + rloc];
    }
}

extern "C" void kernel_launch(void* const* d_in, const int* in_sizes, int n_in,
                              void* d_out, int out_size, void* d_ws, size_t ws_size,
                              hipStream_t stream) {
    const float* X  = (const float*)d_in[0];
    const float* Cc = (const float*)d_in[1];
    const float* PA = (const float*)d_in[2];
    const float* PB = (const float*)d_in[3];

    u16* WA = (u16*)d_ws;                          // 512*576*2 bytes (k-major)
    u16* WB = WA + (size_t)N_OUT * D_TOT;

    float* Z  = (float*)d_out;
    const size_t batch = (size_t)in_sizes[0] / N_OUT;   // 131072
    float* LD = Z + batch * N_OUT;

    prep_weights_kernel<<<N_OUT, 256, 0, stream>>>(PA, PB, WA, WB);

    (void)hipFuncSetAttribute((const void*)maf_main_kernel,
                              hipFuncAttributeMaxDynamicSharedMemorySize,
                              LDS_TOTAL);
    const int grid = (int)(batch / BM);            // 1024
    maf_main_kernel<<<grid, 512, LDS_TOTAL, stream>>>(X, Cc, WA, WB, Z, LD);
}